// Round 10
// baseline (527.462 us; speedup 1.0000x reference)
//
#include <hip/hip_runtime.h>

#define N_NODES    100000
#define N_EDGES    1600000
#define DIM        128
#define OUT_CH     10
#define NUM_GRAPHS 128
#define BN_EPS     1e-5f

#define BSHIFT   8
#define NB2      391
#define CAP2     5120
#define NTILES   782
#define GEMM_GRID 512

typedef __attribute__((ext_vector_type(8))) short short8;
typedef __attribute__((ext_vector_type(4))) float floatx4;

__device__ inline float bf2f(unsigned short u) {
    union { unsigned i; float f; } v; v.i = (unsigned)u << 16; return v.f;
}
__device__ inline unsigned short f2bf(float f) {
    union { float f; unsigned i; } v; v.f = f;
    return (unsigned short)((v.i + 0x8000u) >> 16);   // round-half-up, 2 ops
}

__device__ inline void async_cp16(const unsigned short* g, unsigned short* l) {
    __builtin_amdgcn_global_load_lds(
        (const __attribute__((address_space(1))) void*)g,
        (__attribute__((address_space(3))) void*)l, 16, 0, 0);
}

// ============== cvt x -> bf16, plus workspace zeroing (block 0) ==============
__global__ void k_cvt_x(const float* __restrict__ x, unsigned short* __restrict__ xb,
                        int* __restrict__ gcur, float* __restrict__ stats4,
                        float* __restrict__ pooled) {
    int t = threadIdx.x;
    if (blockIdx.x == 0) {
        for (int i = t; i < NB2 + 1; i += 256) gcur[i] = 0;
        for (int i = t; i < 4 * DIM; i += 256) stats4[i] = 0.f;
        for (int i = t; i < NUM_GRAPHS * DIM; i += 256) pooled[i] = 0.f;
    }
    int idx = blockIdx.x * 256 + t;
    float4 v = ((const float4*)x)[idx];
    ushort4 o;
    o.x = f2bf(v.x); o.y = f2bf(v.y); o.z = f2bf(v.z); o.w = f2bf(v.w);
    ((ushort4*)xb)[idx] = o;
}

__global__ void k_prep_w(const float* __restrict__ W0, const float* __restrict__ W1,
                         const float* __restrict__ W2, const float* __restrict__ W3,
                         unsigned short* __restrict__ Wt) {
    const float* Ws[4] = {W0, W1, W2, W3};
    const float* W = Ws[blockIdx.y];
    unsigned short* o = Wt + blockIdx.y * (DIM * DIM);
    int idx = blockIdx.x * 256 + threadIdx.x;
    int n = idx >> 7, k = idx & 127;
    o[idx] = f2bf(W[k * DIM + n]);
}

// ===================== bucket partition, LDS-staged =====================
__global__ __launch_bounds__(256)
void k_bucket(const int* __restrict__ src, const int* __restrict__ dst,
              int* __restrict__ gcur, unsigned* __restrict__ pairs) {
    __shared__ int cnt[NB2 + 1];
    __shared__ int lofs[NB2 + 1];
    __shared__ int gbase[NB2 + 1];
    __shared__ int scanA[256], scanB[256];
    __shared__ int stage[8192];

    int t = threadIdx.x;
    for (int i = t; i < NB2 + 1; i += 256) cnt[i] = 0;
    __syncthreads();
    int base = blockIdx.x * 8192;
    int n_e = min(8192, N_EDGES - base);
    for (int i = t; i < n_e; i += 256)
        atomicAdd(&cnt[dst[base + i] >> BSHIFT], 1);
    __syncthreads();
    int vA = cnt[t];
    int vB = (t < NB2 - 256) ? cnt[256 + t] : 0;
    scanA[t] = vA; scanB[t] = vB;
    __syncthreads();
    for (int off = 1; off < 256; off <<= 1) {
        int tA = (t >= off) ? scanA[t - off] : 0;
        int tB = (t >= off) ? scanB[t - off] : 0;
        __syncthreads();
        scanA[t] += tA; scanB[t] += tB;
        __syncthreads();
    }
    lofs[t] = scanA[t] - vA;
    if (t < NB2 - 256) lofs[256 + t] = scanA[255] + scanB[t] - vB;
    __syncthreads();
    for (int i = t; i < NB2; i += 256) {
        gbase[i] = (cnt[i] > 0) ? atomicAdd(&gcur[i], cnt[i]) : 0;
        cnt[i] = lofs[i];
    }
    __syncthreads();
    for (int i = t; i < n_e; i += 256) {
        int d = dst[base + i];
        int b = d >> BSHIFT;
        int pos = atomicAdd(&cnt[b], 1);
        stage[pos] = (int)(((unsigned)src[base + i] << 8) | (unsigned)(d & 255));
    }
    __syncthreads();
    int w = t >> 6, lane = t & 63;
    for (int b = w; b < NB2; b += 4) {
        int len = cnt[b] - lofs[b];
        int g0  = gbase[b];
        int maxlen = CAP2 - g0; if (maxlen < 0) maxlen = 0;
        if (len > maxlen) len = maxlen;
        unsigned* dp = pairs + (size_t)b * CAP2 + g0;
        const int* sp = stage + lofs[b];
        for (int i = lane; i < len; i += 64) dp[i] = (unsigned)sp[i];
    }
}

__global__ void k_bscan(const int* __restrict__ gcur, int* __restrict__ bbase,
                        int* __restrict__ row_ptr) {
    __shared__ int sh[512];
    int t = threadIdx.x;
    int v = (t < NB2) ? min(gcur[t], CAP2) : 0;
    sh[t] = v; __syncthreads();
    for (int off = 1; off < 512; off <<= 1) {
        int tmp = (t >= off) ? sh[t - off] : 0;
        __syncthreads();
        sh[t] += tmp;
        __syncthreads();
    }
    if (t < NB2) bbase[t] = sh[t] - v;
    if (t == NB2 - 1) { bbase[NB2] = sh[t]; row_ptr[N_NODES] = sh[t]; }
}

__global__ __launch_bounds__(256)
void k_csr(const unsigned* __restrict__ pairs, const int* __restrict__ gcur,
           const int* __restrict__ bbase, int* __restrict__ row_ptr,
           int* __restrict__ col) {
    __shared__ int hist[256];
    __shared__ int cur[256];
    __shared__ int stage[CAP2];
    int bi = blockIdx.x, t = threadIdx.x;
    hist[t] = 0; __syncthreads();
    int n = min(gcur[bi], CAP2);
    const unsigned* P = pairs + (size_t)bi * CAP2;
    for (int i = t; i < n; i += 256)
        atomicAdd(&hist[P[i] & 255u], 1);
    __syncthreads();
    int self = hist[t];
    cur[t] = self; __syncthreads();
    for (int off = 1; off < 256; off <<= 1) {
        int tmp = (t >= off) ? cur[t - off] : 0;
        __syncthreads();
        cur[t] += tmp;
        __syncthreads();
    }
    int excl = cur[t] - self;
    int base = bbase[bi];
    int node = (bi << 8) + t;
    if (node < N_NODES) row_ptr[node] = base + excl;
    cur[t] = excl;
    __syncthreads();
    for (int i = t; i < n; i += 256) {
        unsigned e = P[i];
        int pos = atomicAdd(&cur[e & 255u], 1);
        stage[pos] = (int)(e >> 8);
    }
    __syncthreads();
    for (int i = t; i < n; i += 256) col[base + i] = stage[i];
}

// ============== Aggregation (node range [n0, n1) — split for profiling) ==============
__global__ void k_agg(const unsigned short* __restrict__ X,
                      unsigned short* __restrict__ Out,
                      const int* __restrict__ row_ptr, const int* __restrict__ col,
                      int n0, int n1) {
    int wid = n0 + ((blockIdx.x * 256 + threadIdx.x) >> 6);
    if (wid >= n1) return;
    int lane = threadIdx.x & 63;
    int half = lane >> 5, m = lane & 31;
    const ushort4* X4 = (const ushort4*)X;

    float a0=0.f,a1=0.f,a2=0.f,a3=0.f;
    float c0=0.f,c1=0.f,c2=0.f,c3=0.f;
    if (half == 0) {
        ushort4 sv = X4[(size_t)wid * 32 + m];
        a0 = bf2f(sv.x); a1 = bf2f(sv.y); a2 = bf2f(sv.z); a3 = bf2f(sv.w);
    }
    int s = row_ptr[wid], e = row_ptr[wid + 1];
    int p = s + half;
    for (; p + 6 < e; p += 8) {
        int v0i = col[p], v1i = col[p + 2], v2i = col[p + 4], v3i = col[p + 6];
        ushort4 v0 = X4[(size_t)v0i * 32 + m];
        ushort4 v1 = X4[(size_t)v1i * 32 + m];
        ushort4 v2 = X4[(size_t)v2i * 32 + m];
        ushort4 v3 = X4[(size_t)v3i * 32 + m];
        a0 += bf2f(v0.x); a1 += bf2f(v0.y); a2 += bf2f(v0.z); a3 += bf2f(v0.w);
        c0 += bf2f(v1.x); c1 += bf2f(v1.y); c2 += bf2f(v1.z); c3 += bf2f(v1.w);
        a0 += bf2f(v2.x); a1 += bf2f(v2.y); a2 += bf2f(v2.z); a3 += bf2f(v2.w);
        c0 += bf2f(v3.x); c1 += bf2f(v3.y); c2 += bf2f(v3.z); c3 += bf2f(v3.w);
    }
    for (; p < e; p += 2) {
        ushort4 v = X4[(size_t)col[p] * 32 + m];
        a0 += bf2f(v.x); a1 += bf2f(v.y); a2 += bf2f(v.z); a3 += bf2f(v.w);
    }
    a0 += c0; a1 += c1; a2 += c2; a3 += c3;
    a0 += __shfl_xor(a0, 32);
    a1 += __shfl_xor(a1, 32);
    a2 += __shfl_xor(a2, 32);
    a3 += __shfl_xor(a3, 32);
    if (half == 0) {
        ushort4 o;
        o.x = f2bf(a0); o.y = f2bf(a1); o.z = f2bf(a2); o.w = f2bf(a3);
        ((ushort4*)Out)[(size_t)wid * 32 + m] = o;
    }
}

// ================= Persistent pipelined MFMA GEMM (GRID 512 = 2 blocks/CU) =================
template<bool BN_LOAD, bool STATS, bool RELU_ST>
__global__ __launch_bounds__(256)
void k_gemm(const unsigned short* __restrict__ In, unsigned short* __restrict__ Out,
            const unsigned short* __restrict__ Wt, const float* __restrict__ bias,
            const float* __restrict__ ssum_in, const float* __restrict__ ssq_in,
            const float* __restrict__ gamma, const float* __restrict__ beta,
            float* __restrict__ ssum_out, float* __restrict__ ssq_out) {
    __shared__ __align__(16) unsigned short sB[128 * 128];   // 32 KB
    __shared__ float ssc[128], ssh[128];
    __shared__ float s_sum[128], s_sq[128];

    int t = threadIdx.x;
    int w = t >> 6, lane = t & 63;
    int m = lane & 15;
    int q = lane >> 4;
    int sw = m & 7;

    #pragma unroll
    for (int u = 0; u < 8; ++u) {
        int i = (w * 8 + u) * 64 + lane;
        int n = i >> 4, p = i & 15;
        async_cp16(Wt + n * 128 + ((p ^ (n & 7)) << 3), sB + (size_t)(w * 8 + u) * 512);
    }
    if (BN_LOAD && t < 128) {
        float mn  = ssum_in[t] * (1.0f / N_NODES);
        float var = ssq_in[t] * (1.0f / N_NODES) - mn * mn;
        float inv = rsqrtf(var + BN_EPS);
        float sc  = gamma[t] * inv;
        ssc[t] = sc; ssh[t] = beta[t] - mn * sc;
    }
    if (STATS && t < 128) { s_sum[t] = 0.f; s_sq[t] = 0.f; }

    int tile = blockIdx.x;
    short8 a0[4], a1[4];
    if (tile < NTILES) {
        int rA0 = min(tile * 128 + w * 32 + m,      N_NODES - 1);
        int rA1 = min(tile * 128 + w * 32 + 16 + m, N_NODES - 1);
        #pragma unroll
        for (int kk = 0; kk < 4; ++kk) {
            a0[kk] = *(const short8*)(In + (size_t)rA0 * 128 + kk * 32 + q * 8);
            a1[kk] = *(const short8*)(In + (size_t)rA1 * 128 + kk * 32 + q * 8);
        }
    }
    __syncthreads();

    #pragma unroll 1
    for (; tile < NTILES; ) {
        int next = tile + GEMM_GRID;
        short8 b0[4], b1[4];
        if (next < NTILES) {
            int rN0 = min(next * 128 + w * 32 + m,      N_NODES - 1);
            int rN1 = min(next * 128 + w * 32 + 16 + m, N_NODES - 1);
            #pragma unroll
            for (int kk = 0; kk < 4; ++kk) {
                b0[kk] = *(const short8*)(In + (size_t)rN0 * 128 + kk * 32 + q * 8);
                b1[kk] = *(const short8*)(In + (size_t)rN1 * 128 + kk * 32 + q * 8);
            }
        }

        if (BN_LOAD) {
            #pragma unroll
            for (int kk = 0; kk < 4; ++kk) {
                int base = kk * 32 + q * 8;
                #pragma unroll
                for (int j = 0; j < 8; ++j) {
                    float scj = ssc[base + j], shj = ssh[base + j];
                    float f0 = fmaxf(bf2f((unsigned short)a0[kk][j]) * scj + shj, 0.f);
                    float f1 = fmaxf(bf2f((unsigned short)a1[kk][j]) * scj + shj, 0.f);
                    a0[kk][j] = (short)f2bf(f0);
                    a1[kk][j] = (short)f2bf(f1);
                }
            }
        }

        floatx4 acc[2][8] = {};
        #pragma unroll
        for (int kk = 0; kk < 4; ++kk) {
            int cp = (kk * 4 + q) ^ sw;
            #pragma unroll
            for (int c = 0; c < 8; ++c) {
                int nr = c * 16 + m;
                short8 b = *(const short8*)&sB[nr * 128 + (cp << 3)];
                acc[0][c] = __builtin_amdgcn_mfma_f32_16x16x32_bf16(b, a0[kk], acc[0][c], 0, 0, 0);
                acc[1][c] = __builtin_amdgcn_mfma_f32_16x16x32_bf16(b, a1[kk], acc[1][c], 0, 0, 0);
            }
        }

        int r0 = tile * 128;
        #pragma unroll
        for (int c = 0; c < 8; ++c) {
            int ch0 = c * 16 + q * 4;
            float4 bv = *(const float4*)(bias + ch0);
            float sr[4] = {0,0,0,0}, qr[4] = {0,0,0,0};
            #pragma unroll
            for (int h = 0; h < 2; ++h) {
                int node = r0 + w * 32 + h * 16 + m;
                float v0 = acc[h][c][0] + bv.x;
                float v1 = acc[h][c][1] + bv.y;
                float v2 = acc[h][c][2] + bv.z;
                float v3 = acc[h][c][3] + bv.w;
                if (RELU_ST) {
                    v0 = fmaxf(v0, 0.f); v1 = fmaxf(v1, 0.f);
                    v2 = fmaxf(v2, 0.f); v3 = fmaxf(v3, 0.f);
                }
                if (node < N_NODES) {
                    ushort4 o;
                    o.x = f2bf(v0); o.y = f2bf(v1); o.z = f2bf(v2); o.w = f2bf(v3);
                    *(ushort4*)(Out + (size_t)node * 128 + ch0) = o;
                    if (STATS) {
                        sr[0] += v0; sr[1] += v1; sr[2] += v2; sr[3] += v3;
                        qr[0] += v0*v0; qr[1] += v1*v1; qr[2] += v2*v2; qr[3] += v3*v3;
                    }
                }
            }
            if (STATS) {
                #pragma unroll
                for (int msk = 1; msk <= 8; msk <<= 1) {
                    #pragma unroll
                    for (int r = 0; r < 4; ++r) {
                        sr[r] += __shfl_xor(sr[r], msk);
                        qr[r] += __shfl_xor(qr[r], msk);
                    }
                }
                if (m == 0) {
                    #pragma unroll
                    for (int r = 0; r < 4; ++r) {
                        atomicAdd(&s_sum[ch0 + r], sr[r]);
                        atomicAdd(&s_sq [ch0 + r], qr[r]);
                    }
                }
            }
        }

        tile = next;
        if (tile < NTILES) {
            #pragma unroll
            for (int kk = 0; kk < 4; ++kk) { a0[kk] = b0[kk]; a1[kk] = b1[kk]; }
        }
    }

    if (STATS) {
        __syncthreads();
        if (t < 128) {
            atomicAdd(&ssum_out[t], s_sum[t]);
            atomicAdd(&ssq_out [t], s_sq[t]);
        }
    }
}

// ============================ Pooling ============================
#define POOL_BLOCKS 512
#define POOL_CHUNK  196
__global__ void k_pool(const unsigned short* __restrict__ h, const int* __restrict__ batch,
                       float* __restrict__ pooled) {
    int c  = threadIdx.x;
    int n0 = blockIdx.x * POOL_CHUNK;
    if (n0 >= N_NODES) return;
    int n1 = min(n0 + POOL_CHUNK, N_NODES);
    int g = batch[n0];
    float acc = 0.f;
    for (int i = n0; i < n1; ++i) {
        int gi = batch[i];
        if (gi != g) { atomicAdd(&pooled[g * DIM + c], acc); acc = 0.f; g = gi; }
        acc += bf2f(h[(size_t)i * DIM + c]);
    }
    atomicAdd(&pooled[g * DIM + c], acc);
}

// ============================ Readout (fused) ============================
__global__ void k_readout(const float* __restrict__ pooled,
                          const float* __restrict__ Wl1, const float* __restrict__ bl1,
                          const float* __restrict__ Wl2, const float* __restrict__ bl2,
                          float* __restrict__ out) {
    __shared__ float p[128], r[128];
    int g = blockIdx.x, c = threadIdx.x;
    p[c] = pooled[g * DIM + c];
    __syncthreads();
    float s = bl1[c];
    #pragma unroll 8
    for (int k = 0; k < DIM; ++k) s += p[k] * Wl1[k * DIM + c];
    r[c] = fmaxf(s, 0.f);
    __syncthreads();
    if (c < OUT_CH) {
        float s2 = bl2[c];
        #pragma unroll 8
        for (int k = 0; k < DIM; ++k) s2 += r[k] * Wl2[k * OUT_CH + c];
        out[g * OUT_CH + c] = s2;
    }
}

// ============================ Launch ============================
extern "C" void kernel_launch(void* const* d_in, const int* in_sizes, int n_in,
                              void* d_out, int out_size, void* d_ws, size_t ws_size,
                              hipStream_t stream) {
    const float* x   = (const float*)d_in[0];
    const int*   ei  = (const int*)d_in[1];
    const int*   bat = (const int*)d_in[2];
    const float* W1a = (const float*)d_in[3];
    const float* b1a = (const float*)d_in[4];
    const float* ga  = (const float*)d_in[5];
    const float* ba  = (const float*)d_in[6];
    const float* W2a = (const float*)d_in[7];
    const float* b2a = (const float*)d_in[8];
    const float* W1b = (const float*)d_in[9];
    const float* b1b = (const float*)d_in[10];
    const float* gb  = (const float*)d_in[11];
    const float* bbt = (const float*)d_in[12];
    const float* W2b = (const float*)d_in[13];
    const float* b2b = (const float*)d_in[14];
    const float* Wl1 = (const float*)d_in[15];
    const float* bl1 = (const float*)d_in[16];
    const float* Wl2 = (const float*)d_in[17];
    const float* bl2 = (const float*)d_in[18];
    float* out = (float*)d_out;

    const int* src = ei;
    const int* dst = ei + N_EDGES;

    char* w = (char*)d_ws;
    size_t off = 0;
    auto alloc = [&](size_t bytes) -> char* {
        char* p = w + off; off += (bytes + 255) & ~(size_t)255; return p;
    };
    unsigned short* xb   = (unsigned short*)alloc((size_t)N_NODES * DIM * 2);
    unsigned short* nb0  = (unsigned short*)alloc((size_t)N_NODES * DIM * 2);
    unsigned short* nb1  = (unsigned short*)alloc((size_t)N_NODES * DIM * 2);
    unsigned short* Wtb  = (unsigned short*)alloc((size_t)4 * DIM * DIM * 2);
    unsigned* pairs = (unsigned*)alloc((size_t)NB2 * CAP2 * 4);
    int*   row_ptr = (int*)  alloc((size_t)(N_NODES + 1) * 4);
    int*   col     = (int*)  alloc((size_t)N_EDGES * 4);
    int*   gcur    = (int*)  alloc((NB2 + 1) * 4);
    int*   bbase   = (int*)  alloc((NB2 + 1) * 4);
    float* stats4  = (float*)alloc((size_t)4 * DIM * 4);
    float* pooled  = (float*)alloc((size_t)NUM_GRAPHS * DIM * 4);
    float* ssumA = stats4, *ssqA = stats4 + DIM, *ssumB = stats4 + 2*DIM, *ssqB = stats4 + 3*DIM;

    k_cvt_x<<<(N_NODES * DIM / 4) / 256, 256, 0, stream>>>(x, xb, gcur, stats4, pooled);
    k_prep_w<<<dim3(64, 4), 256, 0, stream>>>(W1a, W2a, W1b, W2b, Wtb);
    const unsigned short* Wt1a = Wtb;
    const unsigned short* Wt2a = Wtb + DIM * DIM;
    const unsigned short* Wt1b = Wtb + 2 * DIM * DIM;
    const unsigned short* Wt2b = Wtb + 3 * DIM * DIM;

    k_bucket<<<(N_EDGES + 8191) / 8192, 256, 0, stream>>>(src, dst, gcur, pairs);
    k_bscan<<<1, 512, 0, stream>>>(gcur, bbase, row_ptr);
    k_csr<<<NB2, 256, 0, stream>>>(pairs, gcur, bbase, row_ptr, col);

    const int HALF = 50000;
    int agg_blocks = (HALF * 64) / 256;   // 12500

    // conv1
    k_agg<<<agg_blocks, 256, 0, stream>>>(xb, nb0, row_ptr, col, 0, HALF);
    k_agg<<<agg_blocks, 256, 0, stream>>>(xb, nb0, row_ptr, col, HALF, N_NODES);
    k_gemm<false, true, false><<<GEMM_GRID, 256, 0, stream>>>(
        nb0, nb1, Wt1a, b1a, nullptr, nullptr, nullptr, nullptr, ssumA, ssqA);
    k_gemm<true, false, true><<<GEMM_GRID, 256, 0, stream>>>(
        nb1, nb0, Wt2a, b2a, ssumA, ssqA, ga, ba, nullptr, nullptr);
    // conv2
    k_agg<<<agg_blocks, 256, 0, stream>>>(nb0, nb1, row_ptr, col, 0, HALF);
    k_agg<<<agg_blocks, 256, 0, stream>>>(nb0, nb1, row_ptr, col, HALF, N_NODES);
    k_gemm<false, true, false><<<GEMM_GRID, 256, 0, stream>>>(
        nb1, nb0, Wt1b, b1b, nullptr, nullptr, nullptr, nullptr, ssumB, ssqB);
    k_gemm<true, false, true><<<GEMM_GRID, 256, 0, stream>>>(
        nb0, nb1, Wt2b, b2b, ssumB, ssqB, gb, bbt, nullptr, nullptr);
    // readout
    k_pool<<<POOL_BLOCKS, 128, 0, stream>>>(nb1, bat, pooled);
    k_readout<<<NUM_GRAPHS, 128, 0, stream>>>(pooled, Wl1, bl1, Wl2, bl2, out);
}

// Round 11
// 460.329 us; speedup vs baseline: 1.1458x; 1.1458x over previous
//
#include <hip/hip_runtime.h>

#define N_NODES    100000
#define N_EDGES    1600000
#define DIM        128
#define OUT_CH     10
#define NUM_GRAPHS 128
#define BN_EPS     1e-5f

#define BSHIFT   8
#define NB2      391
#define CAP2     5120
#define NTILES   782
#define GEMM_GRID 256

typedef __attribute__((ext_vector_type(8))) short short8;
typedef __attribute__((ext_vector_type(4))) float floatx4;

__device__ inline float bf2f(unsigned short u) {
    union { unsigned i; float f; } v; v.i = (unsigned)u << 16; return v.f;
}
__device__ inline unsigned short f2bf(float f) {
    union { float f; unsigned i; } v; v.f = f;
    return (unsigned short)((v.i + 0x8000u) >> 16);   // round-half-up, 2 ops
}

__device__ inline void async_cp16(const unsigned short* g, unsigned short* l) {
    __builtin_amdgcn_global_load_lds(
        (const __attribute__((address_space(1))) void*)g,
        (__attribute__((address_space(3))) void*)l, 16, 0, 0);
}

// ============== cvt x -> bf16, plus workspace zeroing (block 0) ==============
__global__ void k_cvt_x(const float* __restrict__ x, unsigned short* __restrict__ xb,
                        int* __restrict__ gcur, float* __restrict__ stats4,
                        float* __restrict__ pooled) {
    int t = threadIdx.x;
    if (blockIdx.x == 0) {
        for (int i = t; i < NB2 + 1; i += 256) gcur[i] = 0;
        for (int i = t; i < 4 * DIM; i += 256) stats4[i] = 0.f;
        for (int i = t; i < NUM_GRAPHS * DIM; i += 256) pooled[i] = 0.f;
    }
    int idx = blockIdx.x * 256 + t;
    float4 v = ((const float4*)x)[idx];
    ushort4 o;
    o.x = f2bf(v.x); o.y = f2bf(v.y); o.z = f2bf(v.z); o.w = f2bf(v.w);
    ((ushort4*)xb)[idx] = o;
}

__global__ void k_prep_w(const float* __restrict__ W0, const float* __restrict__ W1,
                         const float* __restrict__ W2, const float* __restrict__ W3,
                         unsigned short* __restrict__ Wt) {
    const float* Ws[4] = {W0, W1, W2, W3};
    const float* W = Ws[blockIdx.y];
    unsigned short* o = Wt + blockIdx.y * (DIM * DIM);
    int idx = blockIdx.x * 256 + threadIdx.x;
    int n = idx >> 7, k = idx & 127;
    o[idx] = f2bf(W[k * DIM + n]);
}

// ===================== bucket partition, LDS-staged =====================
__global__ __launch_bounds__(256)
void k_bucket(const int* __restrict__ src, const int* __restrict__ dst,
              int* __restrict__ gcur, unsigned* __restrict__ pairs) {
    __shared__ int cnt[NB2 + 1];
    __shared__ int lofs[NB2 + 1];
    __shared__ int gbase[NB2 + 1];
    __shared__ int scanA[256], scanB[256];
    __shared__ int stage[8192];

    int t = threadIdx.x;
    for (int i = t; i < NB2 + 1; i += 256) cnt[i] = 0;
    __syncthreads();
    int base = blockIdx.x * 8192;
    int n_e = min(8192, N_EDGES - base);
    for (int i = t; i < n_e; i += 256)
        atomicAdd(&cnt[dst[base + i] >> BSHIFT], 1);
    __syncthreads();
    int vA = cnt[t];
    int vB = (t < NB2 - 256) ? cnt[256 + t] : 0;
    scanA[t] = vA; scanB[t] = vB;
    __syncthreads();
    for (int off = 1; off < 256; off <<= 1) {
        int tA = (t >= off) ? scanA[t - off] : 0;
        int tB = (t >= off) ? scanB[t - off] : 0;
        __syncthreads();
        scanA[t] += tA; scanB[t] += tB;
        __syncthreads();
    }
    lofs[t] = scanA[t] - vA;
    if (t < NB2 - 256) lofs[256 + t] = scanA[255] + scanB[t] - vB;
    __syncthreads();
    for (int i = t; i < NB2; i += 256) {
        gbase[i] = (cnt[i] > 0) ? atomicAdd(&gcur[i], cnt[i]) : 0;
        cnt[i] = lofs[i];
    }
    __syncthreads();
    for (int i = t; i < n_e; i += 256) {
        int d = dst[base + i];
        int b = d >> BSHIFT;
        int pos = atomicAdd(&cnt[b], 1);
        stage[pos] = (int)(((unsigned)src[base + i] << 8) | (unsigned)(d & 255));
    }
    __syncthreads();
    int w = t >> 6, lane = t & 63;
    for (int b = w; b < NB2; b += 4) {
        int len = cnt[b] - lofs[b];
        int g0  = gbase[b];
        int maxlen = CAP2 - g0; if (maxlen < 0) maxlen = 0;
        if (len > maxlen) len = maxlen;
        unsigned* dp = pairs + (size_t)b * CAP2 + g0;
        const int* sp = stage + lofs[b];
        for (int i = lane; i < len; i += 64) dp[i] = (unsigned)sp[i];
    }
}

__global__ void k_bscan(const int* __restrict__ gcur, int* __restrict__ bbase,
                        int* __restrict__ row_ptr) {
    __shared__ int sh[512];
    int t = threadIdx.x;
    int v = (t < NB2) ? min(gcur[t], CAP2) : 0;
    sh[t] = v; __syncthreads();
    for (int off = 1; off < 512; off <<= 1) {
        int tmp = (t >= off) ? sh[t - off] : 0;
        __syncthreads();
        sh[t] += tmp;
        __syncthreads();
    }
    if (t < NB2) bbase[t] = sh[t] - v;
    if (t == NB2 - 1) { bbase[NB2] = sh[t]; row_ptr[N_NODES] = sh[t]; }
}

__global__ __launch_bounds__(256)
void k_csr(const unsigned* __restrict__ pairs, const int* __restrict__ gcur,
           const int* __restrict__ bbase, int* __restrict__ row_ptr,
           int* __restrict__ col) {
    __shared__ int hist[256];
    __shared__ int cur[256];
    __shared__ int stage[CAP2];
    int bi = blockIdx.x, t = threadIdx.x;
    hist[t] = 0; __syncthreads();
    int n = min(gcur[bi], CAP2);
    const unsigned* P = pairs + (size_t)bi * CAP2;
    for (int i = t; i < n; i += 256)
        atomicAdd(&hist[P[i] & 255u], 1);
    __syncthreads();
    int self = hist[t];
    cur[t] = self; __syncthreads();
    for (int off = 1; off < 256; off <<= 1) {
        int tmp = (t >= off) ? cur[t - off] : 0;
        __syncthreads();
        cur[t] += tmp;
        __syncthreads();
    }
    int excl = cur[t] - self;
    int base = bbase[bi];
    int node = (bi << 8) + t;
    if (node < N_NODES) row_ptr[node] = base + excl;
    cur[t] = excl;
    __syncthreads();
    for (int i = t; i < n; i += 256) {
        unsigned e = P[i];
        int pos = atomicAdd(&cur[e & 255u], 1);
        stage[pos] = (int)(e >> 8);
    }
    __syncthreads();
    for (int i = t; i < n; i += 256) col[base + i] = stage[i];
}

// ============================ Aggregation ============================
__global__ void k_agg(const unsigned short* __restrict__ X,
                      unsigned short* __restrict__ Out,
                      const int* __restrict__ row_ptr, const int* __restrict__ col) {
    int wid = (blockIdx.x * 256 + threadIdx.x) >> 6;
    if (wid >= N_NODES) return;
    int lane = threadIdx.x & 63;
    int half = lane >> 5, m = lane & 31;
    const ushort4* X4 = (const ushort4*)X;

    float a0=0.f,a1=0.f,a2=0.f,a3=0.f;
    float c0=0.f,c1=0.f,c2=0.f,c3=0.f;
    if (half == 0) {
        ushort4 sv = X4[(size_t)wid * 32 + m];
        a0 = bf2f(sv.x); a1 = bf2f(sv.y); a2 = bf2f(sv.z); a3 = bf2f(sv.w);
    }
    int s = row_ptr[wid], e = row_ptr[wid + 1];
    int p = s + half;
    for (; p + 6 < e; p += 8) {
        int v0i = col[p], v1i = col[p + 2], v2i = col[p + 4], v3i = col[p + 6];
        ushort4 v0 = X4[(size_t)v0i * 32 + m];
        ushort4 v1 = X4[(size_t)v1i * 32 + m];
        ushort4 v2 = X4[(size_t)v2i * 32 + m];
        ushort4 v3 = X4[(size_t)v3i * 32 + m];
        a0 += bf2f(v0.x); a1 += bf2f(v0.y); a2 += bf2f(v0.z); a3 += bf2f(v0.w);
        c0 += bf2f(v1.x); c1 += bf2f(v1.y); c2 += bf2f(v1.z); c3 += bf2f(v1.w);
        a0 += bf2f(v2.x); a1 += bf2f(v2.y); a2 += bf2f(v2.z); a3 += bf2f(v2.w);
        c0 += bf2f(v3.x); c1 += bf2f(v3.y); c2 += bf2f(v3.z); c3 += bf2f(v3.w);
    }
    for (; p < e; p += 2) {
        ushort4 v = X4[(size_t)col[p] * 32 + m];
        a0 += bf2f(v.x); a1 += bf2f(v.y); a2 += bf2f(v.z); a3 += bf2f(v.w);
    }
    a0 += c0; a1 += c1; a2 += c2; a3 += c3;
    a0 += __shfl_xor(a0, 32);
    a1 += __shfl_xor(a1, 32);
    a2 += __shfl_xor(a2, 32);
    a3 += __shfl_xor(a3, 32);
    if (half == 0) {
        ushort4 o;
        o.x = f2bf(a0); o.y = f2bf(a1); o.z = f2bf(a2); o.w = f2bf(a3);
        ((ushort4*)Out)[(size_t)wid * 32 + m] = o;
    }
}

// ================= Persistent pipelined MFMA GEMM =================
template<bool BN_LOAD, bool STATS, bool RELU_ST>
__global__ __launch_bounds__(256)
void k_gemm(const unsigned short* __restrict__ In, unsigned short* __restrict__ Out,
            const unsigned short* __restrict__ Wt, const float* __restrict__ bias,
            const float* __restrict__ ssum_in, const float* __restrict__ ssq_in,
            const float* __restrict__ gamma, const float* __restrict__ beta,
            float* __restrict__ ssum_out, float* __restrict__ ssq_out) {
    __shared__ __align__(16) unsigned short sB[128 * 128];   // 32 KB
    __shared__ float ssc[128], ssh[128];
    __shared__ float s_sum[128], s_sq[128];

    int t = threadIdx.x;
    int w = t >> 6, lane = t & 63;
    int m = lane & 15;
    int q = lane >> 4;
    int sw = m & 7;

    #pragma unroll
    for (int u = 0; u < 8; ++u) {
        int i = (w * 8 + u) * 64 + lane;
        int n = i >> 4, p = i & 15;
        async_cp16(Wt + n * 128 + ((p ^ (n & 7)) << 3), sB + (size_t)(w * 8 + u) * 512);
    }
    if (BN_LOAD && t < 128) {
        float mn  = ssum_in[t] * (1.0f / N_NODES);
        float var = ssq_in[t] * (1.0f / N_NODES) - mn * mn;
        float inv = rsqrtf(var + BN_EPS);
        float sc  = gamma[t] * inv;
        ssc[t] = sc; ssh[t] = beta[t] - mn * sc;
    }
    if (STATS && t < 128) { s_sum[t] = 0.f; s_sq[t] = 0.f; }

    int tile = blockIdx.x;
    short8 a0[4], a1[4];
    {
        int rA0 = min(tile * 128 + w * 32 + m,      N_NODES - 1);
        int rA1 = min(tile * 128 + w * 32 + 16 + m, N_NODES - 1);
        #pragma unroll
        for (int kk = 0; kk < 4; ++kk) {
            a0[kk] = *(const short8*)(In + (size_t)rA0 * 128 + kk * 32 + q * 8);
            a1[kk] = *(const short8*)(In + (size_t)rA1 * 128 + kk * 32 + q * 8);
        }
    }
    __syncthreads();

    #pragma unroll 1
    for (; tile < NTILES; ) {
        int next = tile + GEMM_GRID;
        short8 b0[4], b1[4];
        if (next < NTILES) {
            int rN0 = min(next * 128 + w * 32 + m,      N_NODES - 1);
            int rN1 = min(next * 128 + w * 32 + 16 + m, N_NODES - 1);
            #pragma unroll
            for (int kk = 0; kk < 4; ++kk) {
                b0[kk] = *(const short8*)(In + (size_t)rN0 * 128 + kk * 32 + q * 8);
                b1[kk] = *(const short8*)(In + (size_t)rN1 * 128 + kk * 32 + q * 8);
            }
        }

        if (BN_LOAD) {
            #pragma unroll
            for (int kk = 0; kk < 4; ++kk) {
                int base = kk * 32 + q * 8;
                #pragma unroll
                for (int j = 0; j < 8; ++j) {
                    float scj = ssc[base + j], shj = ssh[base + j];
                    float f0 = fmaxf(bf2f((unsigned short)a0[kk][j]) * scj + shj, 0.f);
                    float f1 = fmaxf(bf2f((unsigned short)a1[kk][j]) * scj + shj, 0.f);
                    a0[kk][j] = (short)f2bf(f0);
                    a1[kk][j] = (short)f2bf(f1);
                }
            }
        }

        floatx4 acc[2][8] = {};
        #pragma unroll
        for (int kk = 0; kk < 4; ++kk) {
            int cp = (kk * 4 + q) ^ sw;
            #pragma unroll
            for (int c = 0; c < 8; ++c) {
                int nr = c * 16 + m;
                short8 b = *(const short8*)&sB[nr * 128 + (cp << 3)];
                acc[0][c] = __builtin_amdgcn_mfma_f32_16x16x32_bf16(b, a0[kk], acc[0][c], 0, 0, 0);
                acc[1][c] = __builtin_amdgcn_mfma_f32_16x16x32_bf16(b, a1[kk], acc[1][c], 0, 0, 0);
            }
        }

        int r0 = tile * 128;
        #pragma unroll
        for (int c = 0; c < 8; ++c) {
            int ch0 = c * 16 + q * 4;
            float4 bv = *(const float4*)(bias + ch0);
            float sr[4] = {0,0,0,0}, qr[4] = {0,0,0,0};
            #pragma unroll
            for (int h = 0; h < 2; ++h) {
                int node = r0 + w * 32 + h * 16 + m;
                float v0 = acc[h][c][0] + bv.x;
                float v1 = acc[h][c][1] + bv.y;
                float v2 = acc[h][c][2] + bv.z;
                float v3 = acc[h][c][3] + bv.w;
                if (RELU_ST) {
                    v0 = fmaxf(v0, 0.f); v1 = fmaxf(v1, 0.f);
                    v2 = fmaxf(v2, 0.f); v3 = fmaxf(v3, 0.f);
                }
                if (node < N_NODES) {
                    ushort4 o;
                    o.x = f2bf(v0); o.y = f2bf(v1); o.z = f2bf(v2); o.w = f2bf(v3);
                    *(ushort4*)(Out + (size_t)node * 128 + ch0) = o;
                    if (STATS) {
                        sr[0] += v0; sr[1] += v1; sr[2] += v2; sr[3] += v3;
                        qr[0] += v0*v0; qr[1] += v1*v1; qr[2] += v2*v2; qr[3] += v3*v3;
                    }
                }
            }
            if (STATS) {
                #pragma unroll
                for (int msk = 1; msk <= 8; msk <<= 1) {
                    #pragma unroll
                    for (int r = 0; r < 4; ++r) {
                        sr[r] += __shfl_xor(sr[r], msk);
                        qr[r] += __shfl_xor(qr[r], msk);
                    }
                }
                if (m == 0) {
                    #pragma unroll
                    for (int r = 0; r < 4; ++r) {
                        atomicAdd(&s_sum[ch0 + r], sr[r]);
                        atomicAdd(&s_sq [ch0 + r], qr[r]);
                    }
                }
            }
        }

        tile = next;
        if (tile < NTILES) {
            #pragma unroll
            for (int kk = 0; kk < 4; ++kk) { a0[kk] = b0[kk]; a1[kk] = b1[kk]; }
        }
    }

    if (STATS) {
        __syncthreads();
        if (t < 128) {
            atomicAdd(&ssum_out[t], s_sum[t]);
            atomicAdd(&ssq_out [t], s_sq[t]);
        }
    }
}

// ============== Pooling (vectorized: thread = channel-quad x subrow) ==============
#define POOL_BLOCKS 782
#define POOL_CHUNK  128
__global__ __launch_bounds__(256)
void k_pool(const unsigned short* __restrict__ h, const int* __restrict__ batch,
            float* __restrict__ pooled) {
    int t  = threadIdx.x;
    int cq = (t & 31) * 4;      // channel quad base
    int r  = t >> 5;            // subrow 0..7
    int n0 = blockIdx.x * POOL_CHUNK;
    if (n0 >= N_NODES) return;
    int n1 = min(n0 + POOL_CHUNK, N_NODES);
    float a0=0.f, a1=0.f, a2=0.f, a3=0.f;
    int g = -1;
    for (int i = n0 + r; i < n1; i += 8) {
        int gi = batch[i];
        if (gi != g) {
            if (g >= 0) {
                atomicAdd(&pooled[g * DIM + cq + 0], a0);
                atomicAdd(&pooled[g * DIM + cq + 1], a1);
                atomicAdd(&pooled[g * DIM + cq + 2], a2);
                atomicAdd(&pooled[g * DIM + cq + 3], a3);
            }
            a0 = a1 = a2 = a3 = 0.f; g = gi;
        }
        ushort4 v = *(const ushort4*)(h + (size_t)i * DIM + cq);
        a0 += bf2f(v.x); a1 += bf2f(v.y); a2 += bf2f(v.z); a3 += bf2f(v.w);
    }
    if (g >= 0) {
        atomicAdd(&pooled[g * DIM + cq + 0], a0);
        atomicAdd(&pooled[g * DIM + cq + 1], a1);
        atomicAdd(&pooled[g * DIM + cq + 2], a2);
        atomicAdd(&pooled[g * DIM + cq + 3], a3);
    }
}

// ============================ Readout (fused) ============================
__global__ void k_readout(const float* __restrict__ pooled,
                          const float* __restrict__ Wl1, const float* __restrict__ bl1,
                          const float* __restrict__ Wl2, const float* __restrict__ bl2,
                          float* __restrict__ out) {
    __shared__ float p[128], r[128];
    int g = blockIdx.x, c = threadIdx.x;
    p[c] = pooled[g * DIM + c];
    __syncthreads();
    float s = bl1[c];
    #pragma unroll 8
    for (int k = 0; k < DIM; ++k) s += p[k] * Wl1[k * DIM + c];
    r[c] = fmaxf(s, 0.f);
    __syncthreads();
    if (c < OUT_CH) {
        float s2 = bl2[c];
        #pragma unroll 8
        for (int k = 0; k < DIM; ++k) s2 += r[k] * Wl2[k * OUT_CH + c];
        out[g * OUT_CH + c] = s2;
    }
}

// ============================ Launch ============================
extern "C" void kernel_launch(void* const* d_in, const int* in_sizes, int n_in,
                              void* d_out, int out_size, void* d_ws, size_t ws_size,
                              hipStream_t stream) {
    const float* x   = (const float*)d_in[0];
    const int*   ei  = (const int*)d_in[1];
    const int*   bat = (const int*)d_in[2];
    const float* W1a = (const float*)d_in[3];
    const float* b1a = (const float*)d_in[4];
    const float* ga  = (const float*)d_in[5];
    const float* ba  = (const float*)d_in[6];
    const float* W2a = (const float*)d_in[7];
    const float* b2a = (const float*)d_in[8];
    const float* W1b = (const float*)d_in[9];
    const float* b1b = (const float*)d_in[10];
    const float* gb  = (const float*)d_in[11];
    const float* bbt = (const float*)d_in[12];
    const float* W2b = (const float*)d_in[13];
    const float* b2b = (const float*)d_in[14];
    const float* Wl1 = (const float*)d_in[15];
    const float* bl1 = (const float*)d_in[16];
    const float* Wl2 = (const float*)d_in[17];
    const float* bl2 = (const float*)d_in[18];
    float* out = (float*)d_out;

    const int* src = ei;
    const int* dst = ei + N_EDGES;

    char* w = (char*)d_ws;
    size_t off = 0;
    auto alloc = [&](size_t bytes) -> char* {
        char* p = w + off; off += (bytes + 255) & ~(size_t)255; return p;
    };
    unsigned short* xb   = (unsigned short*)alloc((size_t)N_NODES * DIM * 2);
    unsigned short* nb0  = (unsigned short*)alloc((size_t)N_NODES * DIM * 2);
    unsigned short* nb1  = (unsigned short*)alloc((size_t)N_NODES * DIM * 2);
    unsigned short* Wtb  = (unsigned short*)alloc((size_t)4 * DIM * DIM * 2);
    unsigned* pairs = (unsigned*)alloc((size_t)NB2 * CAP2 * 4);
    int*   row_ptr = (int*)  alloc((size_t)(N_NODES + 1) * 4);
    int*   col     = (int*)  alloc((size_t)N_EDGES * 4);
    int*   gcur    = (int*)  alloc((NB2 + 1) * 4);
    int*   bbase   = (int*)  alloc((NB2 + 1) * 4);
    float* stats4  = (float*)alloc((size_t)4 * DIM * 4);
    float* pooled  = (float*)alloc((size_t)NUM_GRAPHS * DIM * 4);
    float* ssumA = stats4, *ssqA = stats4 + DIM, *ssumB = stats4 + 2*DIM, *ssqB = stats4 + 3*DIM;

    k_cvt_x<<<(N_NODES * DIM / 4) / 256, 256, 0, stream>>>(x, xb, gcur, stats4, pooled);
    k_prep_w<<<dim3(64, 4), 256, 0, stream>>>(W1a, W2a, W1b, W2b, Wtb);
    const unsigned short* Wt1a = Wtb;
    const unsigned short* Wt2a = Wtb + DIM * DIM;
    const unsigned short* Wt1b = Wtb + 2 * DIM * DIM;
    const unsigned short* Wt2b = Wtb + 3 * DIM * DIM;

    k_bucket<<<(N_EDGES + 8191) / 8192, 256, 0, stream>>>(src, dst, gcur, pairs);
    k_bscan<<<1, 512, 0, stream>>>(gcur, bbase, row_ptr);
    k_csr<<<NB2, 256, 0, stream>>>(pairs, gcur, bbase, row_ptr, col);

    int agg_blocks = (N_NODES * 64) / 256;

    // conv1
    k_agg<<<agg_blocks, 256, 0, stream>>>(xb, nb0, row_ptr, col);
    k_gemm<false, true, false><<<GEMM_GRID, 256, 0, stream>>>(
        nb0, nb1, Wt1a, b1a, nullptr, nullptr, nullptr, nullptr, ssumA, ssqA);
    k_gemm<true, false, true><<<GEMM_GRID, 256, 0, stream>>>(
        nb1, nb0, Wt2a, b2a, ssumA, ssqA, ga, ba, nullptr, nullptr);
    // conv2
    k_agg<<<agg_blocks, 256, 0, stream>>>(nb0, nb1, row_ptr, col);
    k_gemm<false, true, false><<<GEMM_GRID, 256, 0, stream>>>(
        nb1, nb0, Wt1b, b1b, nullptr, nullptr, nullptr, nullptr, ssumB, ssqB);
    k_gemm<true, false, true><<<GEMM_GRID, 256, 0, stream>>>(
        nb0, nb1, Wt2b, b2b, ssumB, ssqB, gb, bbt, nullptr, nullptr);
    // readout
    k_pool<<<POOL_BLOCKS, 256, 0, stream>>>(nb1, bat, pooled);
    k_readout<<<NUM_GRAPHS, 128, 0, stream>>>(pooled, Wl1, bl1, Wl2, bl2, out);
}